// Round 3
// baseline (44.992 us; speedup 1.0000x reference)
//
#include <hip/hip_runtime.h>

#define ALPHA 0.002
#define NITER 100   // fixed; binary bits of 100 hard-coded below
#define RPT 4       // rows per thread in apply_PQ

typedef float fx4 __attribute__((ext_vector_type(4)));

// Kernel 1: P = M^100, Q = ALPHA * sum_{k=0}^{99} M^k, M = I - ALPHA*A.
// Binary doubling: S_{2n} = S_n + P_n*S_n, P_{2n} = P_n^2 ; odd bit:
// S_{n+1} = S_n + P_n, P_{n+1} = P_n*M.  bits(100) = 1100100 (MSB->LSB).
// One block, 64 threads; thread tid owns (i,j) = (tid>>3, tid&7). fp64.
//   d_ws[0..63]   = P (row-major, fp32)
//   d_ws[64..127] = Q (row-major, fp32)
__global__ __launch_bounds__(64) void build_PQ(const float* __restrict__ A,
                                               float* __restrict__ PQ) {
    const int tid = threadIdx.x;
    const int i = tid >> 3, j = tid & 7;
    __shared__ double Ms[64];
    __shared__ double Ps[64];
    __shared__ double Ss[64];

    const double m = ((i == j) ? 1.0 : 0.0) - (double)ALPHA * (double)A[tid];
    Ms[tid] = m;
    __syncthreads();

    double Mcol[8];
#pragma unroll
    for (int t = 0; t < 8; ++t) Mcol[t] = Ms[t * 8 + j];

    double P = (i == j) ? 1.0 : 0.0;  // P_0 = I
    double S = 0.0;                   // S_0 = 0
    const int bits[7] = {1, 1, 0, 0, 1, 0, 0};  // 100 = 0b1100100

#pragma unroll
    for (int b = 0; b < 7; ++b) {
        Ps[tid] = P;
        Ss[tid] = S;
        __syncthreads();
        double accS = S, accP = 0.0;
#pragma unroll
        for (int t = 0; t < 8; ++t) {
            const double pit = Ps[i * 8 + t];
            accS += pit * Ss[t * 8 + j];   // S + P*S
            accP += pit * Ps[t * 8 + j];   // P*P
        }
        __syncthreads();  // everyone done reading Ps/Ss
        if (bits[b]) {
            S = accS + accP;              // S_{2n} + M^{2n}
            Ps[tid] = accP;               // P_{2n} into LDS for P*M
            __syncthreads();
            double p2 = 0.0;
#pragma unroll
            for (int t = 0; t < 8; ++t) p2 += Ps[i * 8 + t] * Mcol[t];
            P = p2;
            __syncthreads();
        } else {
            S = accS;
            P = accP;
        }
    }

    PQ[tid]      = (float)P;
    PQ[64 + tid] = (float)((double)ALPHA * S);
}

// Kernel 2: out[row] = x[row]*P + y[row]*Q.
// RPT rows per thread; all loads issued before compute (16 fx4 in flight).
// Block covers 256*RPT contiguous rows; within each load, lanes are
// consecutive rows -> fully coalesced. Nontemporal stores for out.
__global__ __launch_bounds__(256) void apply_PQ(const fx4* __restrict__ x4,
                                                const fx4* __restrict__ y4,
                                                const float* __restrict__ PQ,
                                                fx4* __restrict__ out4,
                                                int nrows) {
    __shared__ float sP[64];
    __shared__ float sQ[64];
    if (threadIdx.x < 64) {
        sP[threadIdx.x] = PQ[threadIdx.x];
        sQ[threadIdx.x] = PQ[64 + threadIdx.x];
    }
    __syncthreads();

    const int base = blockIdx.x * (256 * RPT) + threadIdx.x;

    fx4 xv[RPT][2], yv[RPT][2];
    bool act[RPT];
#pragma unroll
    for (int r = 0; r < RPT; ++r) {
        const int row = base + r * 256;
        act[r] = (row < nrows);
        if (act[r]) {
            const size_t p = (size_t)row * 2;
            xv[r][0] = x4[p];
            xv[r][1] = x4[p + 1];
            yv[r][0] = y4[p];
            yv[r][1] = y4[p + 1];
        }
    }

#pragma unroll
    for (int r = 0; r < RPT; ++r) {
        if (!act[r]) continue;
        const float xs[8] = {xv[r][0].x, xv[r][0].y, xv[r][0].z, xv[r][0].w,
                             xv[r][1].x, xv[r][1].y, xv[r][1].z, xv[r][1].w};
        const float ys[8] = {yv[r][0].x, yv[r][0].y, yv[r][0].z, yv[r][0].w,
                             yv[r][1].x, yv[r][1].y, yv[r][1].z, yv[r][1].w};
        float ov[8];
#pragma unroll
        for (int jj = 0; jj < 8; ++jj) {
            float acc = 0.0f;
#pragma unroll
            for (int t = 0; t < 8; ++t) acc = fmaf(xs[t], sP[t * 8 + jj], acc);
#pragma unroll
            for (int t = 0; t < 8; ++t) acc = fmaf(ys[t], sQ[t * 8 + jj], acc);
            ov[jj] = acc;
        }
        const int row = base + r * 256;
        const size_t p = (size_t)row * 2;
        fx4 o0 = {ov[0], ov[1], ov[2], ov[3]};
        fx4 o1 = {ov[4], ov[5], ov[6], ov[7]};
        __builtin_nontemporal_store(o0, &out4[p]);
        __builtin_nontemporal_store(o1, &out4[p + 1]);
    }
}

extern "C" void kernel_launch(void* const* d_in, const int* in_sizes, int n_in,
                              void* d_out, int out_size, void* d_ws, size_t ws_size,
                              hipStream_t stream) {
    const float* x = (const float*)d_in[0];
    const float* y = (const float*)d_in[1];
    const float* A = (const float*)d_in[2];
    float* out = (float*)d_out;
    float* PQ  = (float*)d_ws;  // 128 floats

    const int nrows = in_sizes[0] / 8;  // 2,000,000

    build_PQ<<<1, 64, 0, stream>>>(A, PQ);

    const int rows_per_block = 256 * RPT;
    const int grid = (nrows + rows_per_block - 1) / rows_per_block;
    apply_PQ<<<grid, 256, 0, stream>>>((const fx4*)x, (const fx4*)y, PQ,
                                       (fx4*)out, nrows);
}

// Round 4
// 38.309 us; speedup vs baseline: 1.1745x; 1.1745x over previous
//
#include <hip/hip_runtime.h>

#define ALPHA 0.002
#define NBLK 2048   // persistent grid: 8 blocks/CU on 256 CUs
#define BLK  256

typedef float fx4 __attribute__((ext_vector_type(4)));

// Kernel 1: P = M^100, Q = ALPHA * sum_{k=0}^{99} M^k, M = I - ALPHA*A.
// Binary doubling, fp64, one block of 64 threads. bits(100)=1100100.
//   d_ws[0..63]   = P (row-major, fp32)
//   d_ws[64..127] = Q (row-major, fp32)
__global__ __launch_bounds__(64) void build_PQ(const float* __restrict__ A,
                                               float* __restrict__ PQ) {
    const int tid = threadIdx.x;
    const int i = tid >> 3, j = tid & 7;
    __shared__ double Ms[64];
    __shared__ double Ps[64];
    __shared__ double Ss[64];

    const double m = ((i == j) ? 1.0 : 0.0) - (double)ALPHA * (double)A[tid];
    Ms[tid] = m;
    __syncthreads();

    double Mcol[8];
#pragma unroll
    for (int t = 0; t < 8; ++t) Mcol[t] = Ms[t * 8 + j];

    double P = (i == j) ? 1.0 : 0.0;  // P_0 = I
    double S = 0.0;                   // S_0 = 0
    const int bits[7] = {1, 1, 0, 0, 1, 0, 0};  // 100 = 0b1100100

#pragma unroll
    for (int b = 0; b < 7; ++b) {
        Ps[tid] = P;
        Ss[tid] = S;
        __syncthreads();
        double accS = S, accP = 0.0;
#pragma unroll
        for (int t = 0; t < 8; ++t) {
            const double pit = Ps[i * 8 + t];
            accS += pit * Ss[t * 8 + j];   // S + P*S
            accP += pit * Ps[t * 8 + j];   // P*P
        }
        __syncthreads();
        if (bits[b]) {
            S = accS + accP;
            Ps[tid] = accP;
            __syncthreads();
            double p2 = 0.0;
#pragma unroll
            for (int t = 0; t < 8; ++t) p2 += Ps[i * 8 + t] * Mcol[t];
            P = p2;
            __syncthreads();
        } else {
            S = accS;
            P = accP;
        }
    }

    PQ[tid]      = (float)P;
    PQ[64 + tid] = (float)((double)ALPHA * S);
}

// Kernel 2: out[row] = x[row]*P + y[row]*Q.
// Persistent grid-stride; register double-buffer: next row's 4 loads are
// issued before computing the current row, so each thread keeps 64B in
// flight continuously without the VGPR blowup of RPT=4. Plain stores.
__global__ __launch_bounds__(BLK) void apply_PQ(const fx4* __restrict__ x4,
                                                const fx4* __restrict__ y4,
                                                const float* __restrict__ PQ,
                                                fx4* __restrict__ out4,
                                                int nrows) {
    __shared__ float sP[64];
    __shared__ float sQ[64];
    if (threadIdx.x < 64) {
        sP[threadIdx.x] = PQ[threadIdx.x];
        sQ[threadIdx.x] = PQ[64 + threadIdx.x];
    }
    __syncthreads();

    const int stride = NBLK * BLK;
    int row = blockIdx.x * BLK + threadIdx.x;
    if (row >= nrows) return;

    size_t p = (size_t)row * 2;
    fx4 cx0 = x4[p], cx1 = x4[p + 1];
    fx4 cy0 = y4[p], cy1 = y4[p + 1];

    for (;;) {
        const int nrow = row + stride;
        const bool more = (nrow < nrows);
        fx4 nx0, nx1, ny0, ny1;
        if (more) {
            const size_t np = (size_t)nrow * 2;
            nx0 = x4[np]; nx1 = x4[np + 1];
            ny0 = y4[np]; ny1 = y4[np + 1];
        }

        const float xs[8] = {cx0.x, cx0.y, cx0.z, cx0.w,
                             cx1.x, cx1.y, cx1.z, cx1.w};
        const float ys[8] = {cy0.x, cy0.y, cy0.z, cy0.w,
                             cy1.x, cy1.y, cy1.z, cy1.w};
        float ov[8];
#pragma unroll
        for (int jj = 0; jj < 8; ++jj) {
            float acc = 0.0f;
#pragma unroll
            for (int t = 0; t < 8; ++t) acc = fmaf(xs[t], sP[t * 8 + jj], acc);
#pragma unroll
            for (int t = 0; t < 8; ++t) acc = fmaf(ys[t], sQ[t * 8 + jj], acc);
            ov[jj] = acc;
        }
        fx4 o0 = {ov[0], ov[1], ov[2], ov[3]};
        fx4 o1 = {ov[4], ov[5], ov[6], ov[7]};
        out4[p]     = o0;
        out4[p + 1] = o1;

        if (!more) break;
        row = nrow;
        p = (size_t)row * 2;
        cx0 = nx0; cx1 = nx1; cy0 = ny0; cy1 = ny1;
    }
}

extern "C" void kernel_launch(void* const* d_in, const int* in_sizes, int n_in,
                              void* d_out, int out_size, void* d_ws, size_t ws_size,
                              hipStream_t stream) {
    const float* x = (const float*)d_in[0];
    const float* y = (const float*)d_in[1];
    const float* A = (const float*)d_in[2];
    float* out = (float*)d_out;
    float* PQ  = (float*)d_ws;  // 128 floats

    const int nrows = in_sizes[0] / 8;  // 2,000,000

    build_PQ<<<1, 64, 0, stream>>>(A, PQ);

    apply_PQ<<<NBLK, BLK, 0, stream>>>((const fx4*)x, (const fx4*)y, PQ,
                                       (fx4*)out, nrows);
}

// Round 5
// 37.198 us; speedup vs baseline: 1.2095x; 1.0298x over previous
//
#include <hip/hip_runtime.h>

#define ALPHA 0.002
#define NBLK 2048   // persistent grid: 8 blocks/CU on 256 CUs
#define BLK  256

typedef float fx4 __attribute__((ext_vector_type(4)));

// Single fused kernel.
// Phase 0: each thread issues its first row's x/y loads (kept in flight).
// Phase 1: tid<64 redundantly compute P = M^100 and Q = ALPHA*sum M^k
//          (M = I - ALPHA*A) via binary doubling in fp64 (bits(100)=1100100),
//          publish as fp32 sP/sQ in LDS. All threads hit the same barriers
//          (bits[] is compile-time -> uniform control flow).
// Phase 2: grid-stride streaming with register double-buffer:
//          out[row] = x[row]*P + y[row]*Q.
__global__ __launch_bounds__(BLK) void fused_apply(const fx4* __restrict__ x4,
                                                   const fx4* __restrict__ y4,
                                                   const float* __restrict__ A,
                                                   fx4* __restrict__ out4,
                                                   int nrows) {
    __shared__ double Ms[64];
    __shared__ double Ps[64];
    __shared__ double Ss[64];
    __shared__ float sP[64];
    __shared__ float sQ[64];

    const int tid = threadIdx.x;
    const int stride = NBLK * BLK;

    // ---- Phase 0: issue first row's loads early (hide PQ latency) ----
    int row = blockIdx.x * BLK + tid;          // < nrows always (524288 < 2M)
    size_t p = (size_t)row * 2;
    fx4 cx0 = x4[p], cx1 = x4[p + 1];
    fx4 cy0 = y4[p], cy1 = y4[p + 1];

    // ---- Phase 1: per-block P/Q via binary doubling (tid<64 active) ----
    const int i = tid >> 3, j = tid & 7;
    if (tid < 64)
        Ms[tid] = ((i == j) ? 1.0 : 0.0) - (double)ALPHA * (double)A[tid];
    __syncthreads();

    double Mcol[8];
    if (tid < 64) {
#pragma unroll
        for (int t = 0; t < 8; ++t) Mcol[t] = Ms[t * 8 + j];
    }

    double P = (i == j) ? 1.0 : 0.0;  // P_0 = I   (garbage for tid>=64, unused)
    double S = 0.0;                   // S_0 = 0
    const int bits[7] = {1, 1, 0, 0, 1, 0, 0};  // 100 = 0b1100100

#pragma unroll
    for (int b = 0; b < 7; ++b) {
        if (tid < 64) { Ps[tid] = P; Ss[tid] = S; }
        __syncthreads();
        double accS = S, accP = 0.0;
        if (tid < 64) {
#pragma unroll
            for (int t = 0; t < 8; ++t) {
                const double pit = Ps[i * 8 + t];
                accS += pit * Ss[t * 8 + j];   // S + P*S
                accP += pit * Ps[t * 8 + j];   // P*P
            }
        }
        __syncthreads();
        if (bits[b]) {
            if (tid < 64) { S = accS + accP; Ps[tid] = accP; }
            __syncthreads();
            if (tid < 64) {
                double p2 = 0.0;
#pragma unroll
                for (int t = 0; t < 8; ++t) p2 += Ps[i * 8 + t] * Mcol[t];
                P = p2;
            }
            __syncthreads();
        } else {
            S = accS;
            P = accP;
        }
    }

    if (tid < 64) {
        sP[tid] = (float)P;
        sQ[tid] = (float)((double)ALPHA * S);
    }
    __syncthreads();

    // ---- Phase 2: streaming with register double-buffer ----
    for (;;) {
        const int nrow = row + stride;
        const bool more = (nrow < nrows);
        fx4 nx0, nx1, ny0, ny1;
        if (more) {
            const size_t np = (size_t)nrow * 2;
            nx0 = x4[np]; nx1 = x4[np + 1];
            ny0 = y4[np]; ny1 = y4[np + 1];
        }

        const float xs[8] = {cx0.x, cx0.y, cx0.z, cx0.w,
                             cx1.x, cx1.y, cx1.z, cx1.w};
        const float ys[8] = {cy0.x, cy0.y, cy0.z, cy0.w,
                             cy1.x, cy1.y, cy1.z, cy1.w};
        float ov[8];
#pragma unroll
        for (int jj = 0; jj < 8; ++jj) {
            float acc = 0.0f;
#pragma unroll
            for (int t = 0; t < 8; ++t) acc = fmaf(xs[t], sP[t * 8 + jj], acc);
#pragma unroll
            for (int t = 0; t < 8; ++t) acc = fmaf(ys[t], sQ[t * 8 + jj], acc);
            ov[jj] = acc;
        }
        fx4 o0 = {ov[0], ov[1], ov[2], ov[3]};
        fx4 o1 = {ov[4], ov[5], ov[6], ov[7]};
        out4[p]     = o0;
        out4[p + 1] = o1;

        if (!more) break;
        row = nrow;
        p = (size_t)row * 2;
        cx0 = nx0; cx1 = nx1; cy0 = ny0; cy1 = ny1;
    }
}

extern "C" void kernel_launch(void* const* d_in, const int* in_sizes, int n_in,
                              void* d_out, int out_size, void* d_ws, size_t ws_size,
                              hipStream_t stream) {
    const float* x = (const float*)d_in[0];
    const float* y = (const float*)d_in[1];
    const float* A = (const float*)d_in[2];
    float* out = (float*)d_out;

    const int nrows = in_sizes[0] / 8;  // 2,000,000

    fused_apply<<<NBLK, BLK, 0, stream>>>((const fx4*)x, (const fx4*)y, A,
                                          (fx4*)out, nrows);
}